// Round 7
// baseline (495.277 us; speedup 1.0000x reference)
//
#include <hip/hip_runtime.h>
#include <hip/hip_bf16.h>
#include <stdint.h>
#include <stddef.h>

#define NN 50000
#define NE 800000
#define FIN 500
#define HIDN 64
#define NH 4
#define HCD 16
#define NC 8
// kv row: 64 bf16 Kf*dinv (128 B) + 32 bf16 V (64 B) = 192 B
#define KVROW 192
// S1 row: 64 bf16 K1 (128 B) + 512 fp8 M1 (512 B) = 640 B
#define SROW 640
#define CSTF 1e-5f
#define SCAN_NB 196   // ceil(50000/256)
#define NTILES 782    // ceil(50000/64)

typedef float f32x2 __attribute__((ext_vector_type(2)));
typedef __attribute__((ext_vector_type(8))) short bf16x8;
typedef __attribute__((ext_vector_type(4))) float f32x4;

// bf16 helpers (storage-only; math fp32)
__device__ inline float bf_lo(unsigned u) {
    union { unsigned i; float f; } v; v.i = u << 16; return v.f;
}
__device__ inline float bf_hi(unsigned u) {
    union { unsigned i; float f; } v; v.i = u & 0xffff0000u; return v.f;
}
__device__ inline unsigned short f2bf(float f) {
    union { float f; unsigned i; } v; v.f = f;
    unsigned r = v.i + 0x7fffu + ((v.i >> 16) & 1u);   // RNE
    return (unsigned short)(r >> 16);
}
__device__ inline unsigned pack2bf(float a, float b) {
    __hip_bfloat162 h = __float22bfloat162_rn(make_float2(a, b));
    unsigned r; __builtin_memcpy(&r, &h, 4); return r;
}

// ---------------- degree / CSR build ----------------

__global__ void k_deg(const int* __restrict__ col, int* __restrict__ deg) {
    int e = blockIdx.x * blockDim.x + threadIdx.x;
    if (e < NE) atomicAdd(&deg[col[e]], 1);
}

__global__ void k_deginv(const int* __restrict__ deg, float* __restrict__ dinv,
                         int* __restrict__ cursor, float* __restrict__ tMK) {
    int i = blockIdx.x * blockDim.x + threadIdx.x;
    if (i < NN) {
        dinv[i] = deg[i] > 0 ? 1.0f / (float)deg[i] : 0.0f;
        cursor[i] = 0;
    }
    if (blockIdx.x == 0)
        for (int j = threadIdx.x; j < 576; j += 256) tMK[j] = 0.f;
}

// 3-phase multi-block exclusive scan of deg -> offs
__global__ void k_bsum(const int* __restrict__ deg, int* __restrict__ bsum) {
    __shared__ int red[256];
    int b = blockIdx.x, t = threadIdx.x;
    int i = b * 256 + t;
    red[t] = (i < NN) ? deg[i] : 0;
    __syncthreads();
    for (int d = 128; d > 0; d >>= 1) {
        if (t < d) red[t] += red[t + d];
        __syncthreads();
    }
    if (t == 0) bsum[b] = red[0];
}

__global__ void k_bscan(const int* __restrict__ bsum, int* __restrict__ bex) {
    __shared__ int s[256];
    int t = threadIdx.x;
    int own = (t < SCAN_NB) ? bsum[t] : 0;
    s[t] = own;
    __syncthreads();
    for (int d = 1; d < 256; d <<= 1) {
        int v = (t >= d) ? s[t - d] : 0;
        __syncthreads();
        s[t] += v;
        __syncthreads();
    }
    if (t < SCAN_NB) bex[t] = s[t] - own;   // exclusive
}

__global__ void k_expand(const int* __restrict__ deg, const int* __restrict__ bex,
                         int* __restrict__ offs) {
    __shared__ int s[256];
    int b = blockIdx.x, t = threadIdx.x;
    int i = b * 256 + t;
    int v = (i < NN) ? deg[i] : 0;
    s[t] = v;
    __syncthreads();
    for (int d = 1; d < 256; d <<= 1) {
        int a = (t >= d) ? s[t - d] : 0;
        __syncthreads();
        s[t] += a;
        __syncthreads();
    }
    int excl = s[t] - v + bex[b];
    if (i < NN) offs[i] = excl;
    if (i == NN - 1) offs[NN] = excl + v;
}

__global__ void k_scatter(const int* __restrict__ row, const int* __restrict__ col,
                          const int* __restrict__ offs, int* __restrict__ cursor,
                          int* __restrict__ csr_src) {
    int e = blockIdx.x * blockDim.x + threadIdx.x;
    if (e < NE) {
        int c = col[e];
        int pos = offs[c] + atomicAdd(&cursor[c], 1);
        csr_src[pos] = row[e];
    }
}

// ---------------- x = relu(nf @ Wi + bi), bf16 MFMA, barrier-free K-loop ----
// Whole W (bf16, transposed, XOR-swizzled) resident in LDS: 64 c x 512 k = 64 KB.
// Swizzle: k-block kb (8 bf16 = 16 B) stored at kb ^ (c & 7) -> b128 reads are
// 2-way banked (free). A-fragments loaded directly from global (full 64-B
// lines per row), no staging barrier -> 16 free-running MFMA chunks per tile.

__global__ __launch_bounds__(256) void k_xgemm(const float* __restrict__ nf,
                                               const float* __restrict__ Wi,
                                               const float* __restrict__ bi,
                                               float* __restrict__ x) {
    __shared__ unsigned short w_s[64 * 512];   // 65536 B
    int t = threadIdx.x;
    // stage W transposed + swizzled: 512 kk x 16 c4-groups
    for (int i = t; i < 8192; i += 256) {
        int kk = i >> 4;
        int c4 = (i & 15) * 4;
        float4 v = make_float4(0.f, 0.f, 0.f, 0.f);
        if (kk < FIN) v = *(const float4*)&Wi[(size_t)kk * 64 + c4];
        int kb = kk >> 3, kj = kk & 7;
#pragma unroll
        for (int j = 0; j < 4; j++) {
            int c = c4 + j;
            float val = (j == 0) ? v.x : (j == 1) ? v.y : (j == 2) ? v.z : v.w;
            w_s[c * 512 + ((kb ^ (c & 7)) << 3) + kj] = f2bf(val);
        }
    }
    __syncthreads();

    int lane = t & 63;
    int w = t >> 6;
    int quad = lane >> 4;
    int l15 = lane & 15;

    for (int tile = blockIdx.x; tile < NTILES; tile += gridDim.x) {
        int n0 = tile * 64;
        int rown = n0 + w * 16 + l15;
        const float* arow = &nf[(size_t)(rown < NN ? rown : 0) * FIN];

        f32x4 acc[4];
#pragma unroll
        for (int ct = 0; ct < 4; ct++) acc[ct] = (f32x4){0.f, 0.f, 0.f, 0.f};

        for (int k0 = 0; k0 < 512; k0 += 32) {
            int kk = k0 + quad * 8;
            float4 a0 = make_float4(0.f, 0.f, 0.f, 0.f);
            float4 a1 = make_float4(0.f, 0.f, 0.f, 0.f);
            if (kk < FIN) a0 = *(const float4*)&arow[kk];
            if (kk + 4 < FIN) a1 = *(const float4*)&arow[kk + 4];
            union { unsigned u[4]; bf16x8 v; } A;
            A.u[0] = pack2bf(a0.x, a0.y);
            A.u[1] = pack2bf(a0.z, a0.w);
            A.u[2] = pack2bf(a1.x, a1.y);
            A.u[3] = pack2bf(a1.z, a1.w);
            int kb = kk >> 3;   // = k0/8 + quad
#pragma unroll
            for (int ct = 0; ct < 4; ct++) {
                int c = ct * 16 + l15;
                bf16x8 bfr = *(const bf16x8*)&w_s[c * 512 + ((kb ^ (c & 7)) << 3)];
                acc[ct] = __builtin_amdgcn_mfma_f32_16x16x32_bf16(A.v, bfr, acc[ct], 0, 0, 0);
            }
        }
        // D layout: row = quad*4 + r, col = l15 (per col-tile)
#pragma unroll
        for (int ct = 0; ct < 4; ct++) {
            int c = ct * 16 + l15;
            float bv = bi[c];
#pragma unroll
            for (int r = 0; r < 4; r++) {
                int n = n0 + w * 16 + quad * 4 + r;
                if (n < NN)
                    x[(size_t)n * 64 + c] = fmaxf(acc[ct][r] + bv, 0.f);
            }
        }
    }
}

// ---------------- QKV + kv row + teleport sums ----------------
// kv row: [0..127] Kf*dinv bf16, [128..191] V bf16 (unscaled).
// M0*dinv = (Kf*dinv) (x) V is formed on the fly in k_hop0.

__global__ __launch_bounds__(256) void k_qkv(const float* __restrict__ x,
    const float* __restrict__ Wq, const float* __restrict__ bq,
    const float* __restrict__ Wk, const float* __restrict__ bk,
    const float* __restrict__ Wv, const float* __restrict__ bv,
    const float* __restrict__ hopwise, const float* __restrict__ dinv,
    float* __restrict__ Qg, float* __restrict__ hid,
    unsigned char* __restrict__ kv0, float* __restrict__ tMK) {
    __shared__ float wq_s[64 * 64], wk_s[64 * 64], wv_s[64 * 32];
    __shared__ float bq_s[64], bk_s[64], bv_s[32];
    __shared__ float xs[4][8][64];
    __shared__ float tacc[576];
    int t = threadIdx.x;
    for (int i = t; i < 4096; i += 256) { wq_s[i] = Wq[i]; wk_s[i] = Wk[i]; }
    for (int i = t; i < 2048; i += 256) wv_s[i] = Wv[i];
    if (t < 64) { bq_s[t] = bq[t]; bk_s[t] = bk[t]; }
    if (t >= 64 && t < 96) bv_s[t - 64] = bv[t - 64];
    for (int i = t; i < 576; i += 256) tacc[i] = 0.f;
    __syncthreads();
    int lane = t & 63;
    int w = t >> 6;
    int h = lane >> 4;
    int vcol = lane & 31;
    float hw0 = hopwise[0];
    float tkp = 0.f;
    float tmp_[8];
#pragma unroll
    for (int j = 0; j < 8; j++) tmp_[j] = 0.f;
    int tiles = (NN + 31) >> 5;
    for (int tile = blockIdx.x; tile < tiles; tile += gridDim.x) {
        int n0 = tile * 32 + w * 8;
        __syncthreads();
#pragma unroll
        for (int u = 0; u < 8; u++) {
            int n = n0 + u;
            xs[w][u][lane] = (n < NN) ? x[(size_t)n * 64 + lane] : 0.f;
        }
        __syncthreads();
        float aq[8], ak[8], av[8];
#pragma unroll
        for (int u = 0; u < 8; u++) { aq[u] = 0.f; ak[u] = 0.f; av[u] = 0.f; }
        for (int f = 0; f < 64; f++) {
            float wqv = wq_s[f * 64 + lane];
            float wkv = wk_s[f * 64 + lane];
            float wvv = wv_s[f * 32 + vcol];
#pragma unroll
            for (int u = 0; u < 8; u++) {
                float xf = xs[w][u][f];
                aq[u] = fmaf(xf, wqv, aq[u]);
                ak[u] = fmaf(xf, wkv, ak[u]);
                av[u] = fmaf(xf, wvv, av[u]);
            }
        }
#pragma unroll
        for (int u = 0; u < 8; u++) {
            int n = n0 + u;
            float q = aq[u] + bq_s[lane];
            float k = ak[u] + bk_s[lane];
            float v = av[u] + bv_s[vcol];
            float Qv = q > 0.f ? 1.f + q : expf(q);   // 1 + elu
            float Kv = k > 0.f ? 1.f + k : expf(k);
            if (n < NN) {
                Qg[(size_t)n * 64 + lane] = Qv;
                float vj[8];
#pragma unroll
                for (int j = 0; j < 8; j++) vj[j] = __shfl(v, h * 8 + j, 64);
                tkp += Kv;
#pragma unroll
                for (int j = 0; j < 8; j++) tmp_[j] += Kv * vj[j];
                float dv = dinv[n];
                unsigned short* kvrow = (unsigned short*)(kv0 + (size_t)n * KVROW);
                kvrow[lane] = f2bf(Kv * dv);
                if (lane < 32) kvrow[64 + lane] = f2bf(v);
                if (lane < 32) hid[(size_t)n * 32 + lane] = v * hw0;
            }
        }
    }
#pragma unroll
    for (int j = 0; j < 8; j++) atomicAdd(&tacc[lane * 8 + j], tmp_[j]);
    atomicAdd(&tacc[512 + lane], tkp);
    __syncthreads();
    for (int i = t; i < 576; i += 256) atomicAdd(&tMK[i], tacc[i]);
}

// ---------------- hop 0: gather Kf/V, outer-product on the fly ----------------
// One wave per destination node, unroll-4 edge loop (8 loads in flight).

__global__ __launch_bounds__(256) void k_hop0(const unsigned char* __restrict__ kv0,
    const int* __restrict__ offs, const int* __restrict__ csr_src,
    const float* __restrict__ dinv, const float* __restrict__ Qg,
    const float* __restrict__ hopwise, const float* __restrict__ headwise,
    unsigned char* __restrict__ S1, float* __restrict__ hid) {
    int t = threadIdx.x;
    int lane = t & 63;
    int n = (blockIdx.x * 256 + t) >> 6;
    if (n >= NN) return;
    int h = lane >> 4;
    float e0 = expf(headwise[0]);
    float e1 = expf(headwise[2]);
    float e2 = expf(headwise[4]);
    float e3 = expf(headwise[6]);
    float esum = e0 + e1 + e2 + e3;
    float eh = (h == 0) ? e0 : ((h == 1) ? e1 : ((h == 2) ? e2 : e3));
    float gam = hopwise[1] * eh / esum;

    int hoff = 128 + h * 16;
    int o0 = offs[n], o1 = offs[n + 1];
    float kacc = 0.f;
    float4 m0 = make_float4(0.f, 0.f, 0.f, 0.f);
    float4 m1 = make_float4(0.f, 0.f, 0.f, 0.f);
    int e = o0;
    for (; e + 3 < o1; e += 4) {
        float kk_[4]; uint4 vv[4];
#pragma unroll
        for (int q = 0; q < 4; q++) {
            int s = csr_src[e + q];
            const unsigned char* r = kv0 + (size_t)s * KVROW;
            kk_[q] = bf_lo(((const unsigned short*)r)[lane]);
            vv[q] = *(const uint4*)(r + hoff);
        }
#pragma unroll
        for (int q = 0; q < 4; q++) {
            float ka = kk_[q]; uint4 va = vv[q];
            kacc += ka;
            m0.x = fmaf(ka, bf_lo(va.x), m0.x); m0.y = fmaf(ka, bf_hi(va.x), m0.y);
            m0.z = fmaf(ka, bf_lo(va.y), m0.z); m0.w = fmaf(ka, bf_hi(va.y), m0.w);
            m1.x = fmaf(ka, bf_lo(va.z), m1.x); m1.y = fmaf(ka, bf_hi(va.z), m1.y);
            m1.z = fmaf(ka, bf_lo(va.w), m1.z); m1.w = fmaf(ka, bf_hi(va.w), m1.w);
        }
    }
    for (; e < o1; e++) {
        int s = csr_src[e];
        const unsigned char* r = kv0 + (size_t)s * KVROW;
        float ka = bf_lo(((const unsigned short*)r)[lane]);
        uint4 va = *(const uint4*)(r + hoff);
        kacc += ka;
        m0.x = fmaf(ka, bf_lo(va.x), m0.x); m0.y = fmaf(ka, bf_hi(va.x), m0.y);
        m0.z = fmaf(ka, bf_lo(va.y), m0.z); m0.w = fmaf(ka, bf_hi(va.y), m0.w);
        m1.x = fmaf(ka, bf_lo(va.z), m1.x); m1.y = fmaf(ka, bf_hi(va.z), m1.y);
        m1.z = fmaf(ka, bf_lo(va.w), m1.z); m1.w = fmaf(ka, bf_hi(va.w), m1.w);
    }
    // write S1: K1 bf16 (*dinv), M1 fp8 (*dinv*16; 1/16 folded into hop-1 gamma)
    {
        float dv = dinv[n];
        float s16 = dv * 16.f;
        unsigned char* drow = S1 + (size_t)n * SROW;
        ((unsigned short*)drow)[lane] = f2bf(kacc * dv);
        unsigned u0 = __builtin_amdgcn_cvt_pk_fp8_f32(m0.x * s16, m0.y * s16, 0, false);
        u0 = __builtin_amdgcn_cvt_pk_fp8_f32(m0.z * s16, m0.w * s16, u0, true);
        unsigned u1 = __builtin_amdgcn_cvt_pk_fp8_f32(m1.x * s16, m1.y * s16, 0, false);
        u1 = __builtin_amdgcn_cvt_pk_fp8_f32(m1.z * s16, m1.w * s16, u1, true);
        uint2 pv; pv.x = u0; pv.y = u1;
        *(uint2*)(drow + 128 + lane * 8) = pv;
    }
    // attend
    float qv = Qg[(size_t)n * 64 + lane];
    float hh[8];
    hh[0] = qv * m0.x; hh[1] = qv * m0.y; hh[2] = qv * m0.z; hh[3] = qv * m0.w;
    hh[4] = qv * m1.x; hh[5] = qv * m1.y; hh[6] = qv * m1.z; hh[7] = qv * m1.w;
    float cc = qv * kacc;
#pragma unroll
    for (int s = 1; s < 16; s <<= 1) {
#pragma unroll
        for (int j = 0; j < 8; j++) hh[j] += __shfl_xor(hh[j], s, 16);
        cc += __shfl_xor(cc, s, 16);
    }
    if ((lane & 15) < 8) {
        int j = lane & 7;
        float val = j < 4 ? (j < 2 ? (j == 0 ? hh[0] : hh[1]) : (j == 2 ? hh[2] : hh[3]))
                          : (j < 6 ? (j == 4 ? hh[4] : hh[5]) : (j == 6 ? hh[6] : hh[7]));
        size_t idx = (size_t)n * 32 + h * 8 + j;
        hid[idx] += gam * val / (cc + CSTF);
    }
}

// ---------------- hop 1: gather S1 (bf16 K + fp8 M), attend, unroll-4 --------

__global__ __launch_bounds__(256) void k_prop1(const unsigned char* __restrict__ Sold,
    const int* __restrict__ offs, const int* __restrict__ csr_src,
    const float* __restrict__ Qg, const float* __restrict__ hopwise,
    const float* __restrict__ headwise, float* __restrict__ hid) {
    int t = threadIdx.x;
    int lane = t & 63;
    int n = (blockIdx.x * 256 + t) >> 6;
    if (n >= NN) return;
    int h = lane >> 4;
    float e0 = expf(headwise[1]);
    float e1 = expf(headwise[3]);
    float e2 = expf(headwise[5]);
    float e3 = expf(headwise[7]);
    float esum = e0 + e1 + e2 + e3;
    float eh = (h == 0) ? e0 : ((h == 1) ? e1 : ((h == 2) ? e2 : e3));
    float gam = hopwise[2] * eh / esum * 0.0625f;   // 1/16 M-scale folded in

    int o0 = offs[n], o1 = offs[n + 1];
    float kacc = 0.f;
    float4 m0 = make_float4(0.f, 0.f, 0.f, 0.f);
    float4 m1 = make_float4(0.f, 0.f, 0.f, 0.f);
    int e = o0;
    for (; e + 3 < o1; e += 4) {
        float kk_[4]; uint2 mv[4];
#pragma unroll
        for (int q = 0; q < 4; q++) {
            int s = csr_src[e + q];
            const unsigned char* r = Sold + (size_t)s * SROW;
            kk_[q] = bf_lo(((const unsigned short*)r)[lane]);
            mv[q] = *(const uint2*)(r + 128 + lane * 8);
        }
#pragma unroll
        for (int q = 0; q < 4; q++) {
            kacc += kk_[q];
            f32x2 a0 = __builtin_amdgcn_cvt_pk_f32_fp8(mv[q].x, false);
            f32x2 a1 = __builtin_amdgcn_cvt_pk_f32_fp8(mv[q].x, true);
            f32x2 b0 = __builtin_amdgcn_cvt_pk_f32_fp8(mv[q].y, false);
            f32x2 b1 = __builtin_amdgcn_cvt_pk_f32_fp8(mv[q].y, true);
            m0.x += a0.x; m0.y += a0.y; m0.z += a1.x; m0.w += a1.y;
            m1.x += b0.x; m1.y += b0.y; m1.z += b1.x; m1.w += b1.y;
        }
    }
    for (; e < o1; e++) {
        int s = csr_src[e];
        const unsigned char* r = Sold + (size_t)s * SROW;
        float ka = bf_lo(((const unsigned short*)r)[lane]);
        uint2 mva = *(const uint2*)(r + 128 + lane * 8);
        kacc += ka;
        f32x2 a0 = __builtin_amdgcn_cvt_pk_f32_fp8(mva.x, false);
        f32x2 a1 = __builtin_amdgcn_cvt_pk_f32_fp8(mva.x, true);
        f32x2 b0 = __builtin_amdgcn_cvt_pk_f32_fp8(mva.y, false);
        f32x2 b1 = __builtin_amdgcn_cvt_pk_f32_fp8(mva.y, true);
        m0.x += a0.x; m0.y += a0.y; m0.z += a1.x; m0.w += a1.y;
        m1.x += b0.x; m1.y += b0.y; m1.z += b1.x; m1.w += b1.y;
    }
    float qv = Qg[(size_t)n * 64 + lane];
    float hh[8];
    hh[0] = qv * m0.x; hh[1] = qv * m0.y; hh[2] = qv * m0.z; hh[3] = qv * m0.w;
    hh[4] = qv * m1.x; hh[5] = qv * m1.y; hh[6] = qv * m1.z; hh[7] = qv * m1.w;
    float cc = qv * kacc;
#pragma unroll
    for (int s = 1; s < 16; s <<= 1) {
#pragma unroll
        for (int j = 0; j < 8; j++) hh[j] += __shfl_xor(hh[j], s, 16);
        cc += __shfl_xor(cc, s, 16);
    }
    if ((lane & 15) < 8) {
        int j = lane & 7;
        float val = j < 4 ? (j < 2 ? (j == 0 ? hh[0] : hh[1]) : (j == 2 ? hh[2] : hh[3]))
                          : (j < 6 ? (j == 4 ? hh[4] : hh[5]) : (j == 6 ? hh[6] : hh[7]));
        size_t idx = (size_t)n * 32 + h * 8 + j;
        hid[idx] += gam * val / (cc + CSTF);
    }
}

// ---------------- final: out = hidden @ Wo + bo + teleport * teleportH ----------------

__global__ __launch_bounds__(256) void k_final(const float* __restrict__ hid,
    const float* __restrict__ Qg, const float* __restrict__ Wo,
    const float* __restrict__ bo, const float* __restrict__ tMK,
    const float* __restrict__ teleport, float* __restrict__ out) {
    __shared__ float tm[512];
    __shared__ float tk[64];
    __shared__ float wo[256];
    __shared__ float bos[8];
    int t = threadIdx.x;
    const float invN = 1.0f / (float)NN;
    for (int i = t; i < 512; i += 256) tm[i] = tMK[i] * invN;
    if (t < 64) tk[t] = tMK[512 + t] * invN;
    wo[t] = Wo[t & 255];
    if (t < 8) bos[t] = bo[t];
    __syncthreads();
    float tp = teleport[0];
    int lane = t & 63;
    int sub = lane & 7;
    int g = lane >> 3;
    int wid = (blockIdx.x * 256 + t) >> 6;
    int nwaves = gridDim.x * 4;
    for (int nb = wid * 8; nb < NN; nb += nwaves * 8) {
        int n = nb + g;
        if (n < NN) {
            const float* hrow = hid + (size_t)n * 32;
            const float* qrow = Qg + (size_t)n * 64;
            float o = bos[sub];
#pragma unroll
            for (int m = 0; m < 32; m++) o = fmaf(hrow[m], wo[m * 8 + sub], o);
            float th = 0.f;
#pragma unroll
            for (int h2 = 0; h2 < 4; h2++) {
                float num = 0.f, den = 0.f;
#pragma unroll
                for (int i = 0; i < 16; i++) {
                    float q = qrow[h2 * 16 + i];
                    num = fmaf(q, tm[h2 * 128 + i * 8 + sub], num);
                    den = fmaf(q, tk[h2 * 16 + i], den);
                }
                th += num / (den + CSTF);
            }
            out[(size_t)n * 8 + sub] = o + tp * th;
        }
    }
}

// ---------------- launch ----------------

extern "C" void kernel_launch(void* const* d_in, const int* in_sizes, int n_in,
                              void* d_out, int out_size, void* d_ws, size_t ws_size,
                              hipStream_t stream) {
    const float* nf = (const float*)d_in[0];
    const int* ei = (const int*)d_in[1];
    const float* Wi = (const float*)d_in[2];
    const float* bi = (const float*)d_in[3];
    const float* Wq = (const float*)d_in[4];
    const float* bq = (const float*)d_in[5];
    const float* Wk = (const float*)d_in[6];
    const float* bk = (const float*)d_in[7];
    const float* Wv = (const float*)d_in[8];
    const float* bv = (const float*)d_in[9];
    const float* Wo = (const float*)d_in[10];
    const float* bo = (const float*)d_in[11];
    const float* hopwise = (const float*)d_in[12];
    const float* headwise = (const float*)d_in[13];
    const float* teleport = (const float*)d_in[14];
    float* out = (float*)d_out;

    char* base = (char*)d_ws;
    size_t off = 0;
    auto alloc = [&](size_t bytes) -> void* {
        void* p = base + off;
        off = (off + bytes + 255) & ~(size_t)255;
        return p;
    };
    int* deg = (int*)alloc(NN * 4);
    int* cursor = (int*)alloc(NN * 4);
    int* offs = (int*)alloc((NN + 1) * 4);
    int* bsum = (int*)alloc(256 * 4);
    int* bex = (int*)alloc(256 * 4);
    float* dinv = (float*)alloc(NN * 4);
    int* csr_src = (int*)alloc((size_t)NE * 4);
    float* xbuf = (float*)alloc((size_t)NN * 64 * 4);
    float* Qg = (float*)alloc((size_t)NN * 64 * 4);
    float* hid = (float*)alloc((size_t)NN * 32 * 4);
    unsigned char* kv0 = (unsigned char*)alloc((size_t)NN * KVROW);
    unsigned char* S1 = (unsigned char*)alloc((size_t)NN * SROW);
    float* tMK = (float*)alloc(576 * 4);

    const int* rowp = ei;
    const int* colp = ei + NE;

    hipMemsetAsync(deg, 0, NN * 4, stream);

    k_deg<<<(NE + 255) / 256, 256, 0, stream>>>(colp, deg);
    k_deginv<<<(NN + 255) / 256, 256, 0, stream>>>(deg, dinv, cursor, tMK);
    k_bsum<<<SCAN_NB, 256, 0, stream>>>(deg, bsum);
    k_bscan<<<1, 256, 0, stream>>>(bsum, bex);
    k_expand<<<SCAN_NB, 256, 0, stream>>>(deg, bex, offs);
    k_scatter<<<(NE + 255) / 256, 256, 0, stream>>>(rowp, colp, offs, cursor, csr_src);
    k_xgemm<<<512, 256, 0, stream>>>(nf, Wi, bi, xbuf);
    k_qkv<<<512, 256, 0, stream>>>(xbuf, Wq, bq, Wk, bk, Wv, bv, hopwise, dinv,
                                   Qg, hid, kv0, tMK);
    k_hop0<<<(NN * 64 + 255) / 256, 256, 0, stream>>>(kv0, offs, csr_src, dinv, Qg,
                                                      hopwise, headwise, S1, hid);
    k_prop1<<<(NN * 64 + 255) / 256, 256, 0, stream>>>(S1, offs, csr_src, Qg,
                                                       hopwise, headwise, hid);
    k_final<<<1563, 256, 0, stream>>>(hid, Qg, Wo, bo, tMK, teleport, out);
}

// Round 8
// 480.609 us; speedup vs baseline: 1.0305x; 1.0305x over previous
//
#include <hip/hip_runtime.h>
#include <hip/hip_bf16.h>
#include <stdint.h>
#include <stddef.h>

#define NN 50000
#define NE 800000
#define FIN 500
#define HIDN 64
#define NH 4
#define HCD 16
#define NC 8
// kv row: 64 bf16 Kf*dinv (128 B) + 32 bf16 V (64 B) = 192 B
#define KVROW 192
// S1 row: 64 bf16 K1 (128 B) + 512 fp8 M1 (512 B) = 640 B
#define SROW 640
#define CSTF 1e-5f
#define SCAN_NB 196   // ceil(50000/256)
#define NTILES 782    // ceil(50000/64)

typedef float f32x2 __attribute__((ext_vector_type(2)));
typedef __attribute__((ext_vector_type(8))) short bf16x8;
typedef __attribute__((ext_vector_type(4))) float f32x4;

// bf16 helpers (storage-only; math fp32)
__device__ inline float bf_lo(unsigned u) {
    union { unsigned i; float f; } v; v.i = u << 16; return v.f;
}
__device__ inline float bf_hi(unsigned u) {
    union { unsigned i; float f; } v; v.i = u & 0xffff0000u; return v.f;
}
__device__ inline unsigned short f2bf(float f) {
    union { float f; unsigned i; } v; v.f = f;
    unsigned r = v.i + 0x7fffu + ((v.i >> 16) & 1u);   // RNE
    return (unsigned short)(r >> 16);
}
__device__ inline unsigned pack2bf(float a, float b) {
    __hip_bfloat162 h = __float22bfloat162_rn(make_float2(a, b));
    unsigned r; __builtin_memcpy(&r, &h, 4); return r;
}

// ---------------- degree / CSR build ----------------

__global__ void k_deg(const int* __restrict__ col, int* __restrict__ deg) {
    int e = blockIdx.x * blockDim.x + threadIdx.x;
    if (e < NE) atomicAdd(&deg[col[e]], 1);
}

__global__ void k_deginv(const int* __restrict__ deg, float* __restrict__ dinv,
                         int* __restrict__ cursor, float* __restrict__ tMK) {
    int i = blockIdx.x * blockDim.x + threadIdx.x;
    if (i < NN) {
        dinv[i] = deg[i] > 0 ? 1.0f / (float)deg[i] : 0.0f;
        cursor[i] = 0;
    }
    if (blockIdx.x == 0)
        for (int j = threadIdx.x; j < 576; j += 256) tMK[j] = 0.f;
}

// 3-phase multi-block exclusive scan of deg -> offs
__global__ void k_bsum(const int* __restrict__ deg, int* __restrict__ bsum) {
    __shared__ int red[256];
    int b = blockIdx.x, t = threadIdx.x;
    int i = b * 256 + t;
    red[t] = (i < NN) ? deg[i] : 0;
    __syncthreads();
    for (int d = 128; d > 0; d >>= 1) {
        if (t < d) red[t] += red[t + d];
        __syncthreads();
    }
    if (t == 0) bsum[b] = red[0];
}

__global__ void k_bscan(const int* __restrict__ bsum, int* __restrict__ bex) {
    __shared__ int s[256];
    int t = threadIdx.x;
    int own = (t < SCAN_NB) ? bsum[t] : 0;
    s[t] = own;
    __syncthreads();
    for (int d = 1; d < 256; d <<= 1) {
        int v = (t >= d) ? s[t - d] : 0;
        __syncthreads();
        s[t] += v;
        __syncthreads();
    }
    if (t < SCAN_NB) bex[t] = s[t] - own;   // exclusive
}

__global__ void k_expand(const int* __restrict__ deg, const int* __restrict__ bex,
                         int* __restrict__ offs) {
    __shared__ int s[256];
    int b = blockIdx.x, t = threadIdx.x;
    int i = b * 256 + t;
    int v = (i < NN) ? deg[i] : 0;
    s[t] = v;
    __syncthreads();
    for (int d = 1; d < 256; d <<= 1) {
        int a = (t >= d) ? s[t - d] : 0;
        __syncthreads();
        s[t] += a;
        __syncthreads();
    }
    int excl = s[t] - v + bex[b];
    if (i < NN) offs[i] = excl;
    if (i == NN - 1) offs[NN] = excl + v;
}

__global__ void k_scatter(const int* __restrict__ row, const int* __restrict__ col,
                          const int* __restrict__ offs, int* __restrict__ cursor,
                          int* __restrict__ csr_src) {
    int e = blockIdx.x * blockDim.x + threadIdx.x;
    if (e < NE) {
        int c = col[e];
        int pos = offs[c] + atomicAdd(&cursor[c], 1);
        csr_src[pos] = row[e];
    }
}

// ---------------- Wt: transpose Wi -> bf16, k-major [c][k], k padded to 512 ----

__global__ void k_wt(const float* __restrict__ Wi, unsigned short* __restrict__ Wt) {
    int i = blockIdx.x * blockDim.x + threadIdx.x;   // 32768 threads
    if (i < 64 * 512) {
        int c = i >> 9;
        int k = i & 511;
        Wt[i] = (k < FIN) ? f2bf(Wi[(size_t)k * 64 + c]) : (unsigned short)0;
    }
}

// ---------------- x = relu(nf @ Wi + bi), bf16 MFMA, NO LDS ----------------
// One block = 64 rows; wave w owns rows w*16..w*16+15, 4 col-tiles of 16.
// A-fragments: direct global loads (row-contiguous 32 B per lane per chunk).
// B-fragments: direct global loads from Wt (16 B contiguous; 64 KB total ->
// L2-resident on every XCD). No barriers, no bank conflicts, no LDS cap.

__global__ __launch_bounds__(256) void k_xgemm(const float* __restrict__ nf,
                                               const unsigned short* __restrict__ Wt,
                                               const float* __restrict__ bi,
                                               float* __restrict__ x) {
    int t = threadIdx.x;
    int lane = t & 63;
    int w = t >> 6;
    int quad = lane >> 4;
    int l15 = lane & 15;
    int n0 = blockIdx.x * 64;
    int rown = n0 + w * 16 + l15;
    const float* arow = &nf[(size_t)(rown < NN ? rown : 0) * FIN];

    f32x4 acc[4];
#pragma unroll
    for (int ct = 0; ct < 4; ct++) acc[ct] = (f32x4){0.f, 0.f, 0.f, 0.f};

    for (int k0 = 0; k0 < 512; k0 += 32) {
        int kk = k0 + quad * 8;
        float4 a0 = make_float4(0.f, 0.f, 0.f, 0.f);
        float4 a1 = make_float4(0.f, 0.f, 0.f, 0.f);
        if (kk < FIN) a0 = *(const float4*)&arow[kk];
        if (kk + 4 < FIN) a1 = *(const float4*)&arow[kk + 4];
        union { unsigned u[4]; bf16x8 v; } A;
        A.u[0] = pack2bf(a0.x, a0.y);
        A.u[1] = pack2bf(a0.z, a0.w);
        A.u[2] = pack2bf(a1.x, a1.y);
        A.u[3] = pack2bf(a1.z, a1.w);
#pragma unroll
        for (int ct = 0; ct < 4; ct++) {
            int c = ct * 16 + l15;
            bf16x8 bfr = *(const bf16x8*)&Wt[(size_t)c * 512 + kk];
            acc[ct] = __builtin_amdgcn_mfma_f32_16x16x32_bf16(A.v, bfr, acc[ct], 0, 0, 0);
        }
    }
    // D layout: row = quad*4 + r, col = l15 (per col-tile)
#pragma unroll
    for (int ct = 0; ct < 4; ct++) {
        int c = ct * 16 + l15;
        float bv = bi[c];
#pragma unroll
        for (int r = 0; r < 4; r++) {
            int n = n0 + w * 16 + quad * 4 + r;
            if (n < NN)
                x[(size_t)n * 64 + c] = fmaxf(acc[ct][r] + bv, 0.f);
        }
    }
}

// ---------------- QKV + kv row + teleport sums ----------------
// kv row: [0..127] Kf*dinv bf16, [128..191] V bf16 (unscaled).
// M0*dinv = (Kf*dinv) (x) V is formed on the fly in k_hop0.

__global__ __launch_bounds__(256) void k_qkv(const float* __restrict__ x,
    const float* __restrict__ Wq, const float* __restrict__ bq,
    const float* __restrict__ Wk, const float* __restrict__ bk,
    const float* __restrict__ Wv, const float* __restrict__ bv,
    const float* __restrict__ hopwise, const float* __restrict__ dinv,
    float* __restrict__ Qg, float* __restrict__ hid,
    unsigned char* __restrict__ kv0, float* __restrict__ tMK) {
    __shared__ float wq_s[64 * 64], wk_s[64 * 64], wv_s[64 * 32];
    __shared__ float bq_s[64], bk_s[64], bv_s[32];
    __shared__ float xs[4][8][64];
    __shared__ float tacc[576];
    int t = threadIdx.x;
    for (int i = t; i < 4096; i += 256) { wq_s[i] = Wq[i]; wk_s[i] = Wk[i]; }
    for (int i = t; i < 2048; i += 256) wv_s[i] = Wv[i];
    if (t < 64) { bq_s[t] = bq[t]; bk_s[t] = bk[t]; }
    if (t >= 64 && t < 96) bv_s[t - 64] = bv[t - 64];
    for (int i = t; i < 576; i += 256) tacc[i] = 0.f;
    __syncthreads();
    int lane = t & 63;
    int w = t >> 6;
    int h = lane >> 4;
    int vcol = lane & 31;
    float hw0 = hopwise[0];
    float tkp = 0.f;
    float tmp_[8];
#pragma unroll
    for (int j = 0; j < 8; j++) tmp_[j] = 0.f;
    int tiles = (NN + 31) >> 5;
    for (int tile = blockIdx.x; tile < tiles; tile += gridDim.x) {
        int n0 = tile * 32 + w * 8;
        __syncthreads();
#pragma unroll
        for (int u = 0; u < 8; u++) {
            int n = n0 + u;
            xs[w][u][lane] = (n < NN) ? x[(size_t)n * 64 + lane] : 0.f;
        }
        __syncthreads();
        float aq[8], ak[8], av[8];
#pragma unroll
        for (int u = 0; u < 8; u++) { aq[u] = 0.f; ak[u] = 0.f; av[u] = 0.f; }
        for (int f = 0; f < 64; f++) {
            float wqv = wq_s[f * 64 + lane];
            float wkv = wk_s[f * 64 + lane];
            float wvv = wv_s[f * 32 + vcol];
#pragma unroll
            for (int u = 0; u < 8; u++) {
                float xf = xs[w][u][f];
                aq[u] = fmaf(xf, wqv, aq[u]);
                ak[u] = fmaf(xf, wkv, ak[u]);
                av[u] = fmaf(xf, wvv, av[u]);
            }
        }
#pragma unroll
        for (int u = 0; u < 8; u++) {
            int n = n0 + u;
            float q = aq[u] + bq_s[lane];
            float k = ak[u] + bk_s[lane];
            float v = av[u] + bv_s[vcol];
            float Qv = q > 0.f ? 1.f + q : expf(q);   // 1 + elu
            float Kv = k > 0.f ? 1.f + k : expf(k);
            if (n < NN) {
                Qg[(size_t)n * 64 + lane] = Qv;
                float vj[8];
#pragma unroll
                for (int j = 0; j < 8; j++) vj[j] = __shfl(v, h * 8 + j, 64);
                tkp += Kv;
#pragma unroll
                for (int j = 0; j < 8; j++) tmp_[j] += Kv * vj[j];
                float dv = dinv[n];
                unsigned short* kvrow = (unsigned short*)(kv0 + (size_t)n * KVROW);
                kvrow[lane] = f2bf(Kv * dv);
                if (lane < 32) kvrow[64 + lane] = f2bf(v);
                if (lane < 32) hid[(size_t)n * 32 + lane] = v * hw0;
            }
        }
    }
#pragma unroll
    for (int j = 0; j < 8; j++) atomicAdd(&tacc[lane * 8 + j], tmp_[j]);
    atomicAdd(&tacc[512 + lane], tkp);
    __syncthreads();
    for (int i = t; i < 576; i += 256) atomicAdd(&tMK[i], tacc[i]);
}

// ---------------- hop 0: gather Kf/V, outer-product on the fly ----------------
// One wave per destination node, unroll-4 edge loop (8 loads in flight).

__global__ __launch_bounds__(256) void k_hop0(const unsigned char* __restrict__ kv0,
    const int* __restrict__ offs, const int* __restrict__ csr_src,
    const float* __restrict__ dinv, const float* __restrict__ Qg,
    const float* __restrict__ hopwise, const float* __restrict__ headwise,
    unsigned char* __restrict__ S1, float* __restrict__ hid) {
    int t = threadIdx.x;
    int lane = t & 63;
    int n = (blockIdx.x * 256 + t) >> 6;
    if (n >= NN) return;
    int h = lane >> 4;
    float e0 = expf(headwise[0]);
    float e1 = expf(headwise[2]);
    float e2 = expf(headwise[4]);
    float e3 = expf(headwise[6]);
    float esum = e0 + e1 + e2 + e3;
    float eh = (h == 0) ? e0 : ((h == 1) ? e1 : ((h == 2) ? e2 : e3));
    float gam = hopwise[1] * eh / esum;

    int hoff = 128 + h * 16;
    int o0 = offs[n], o1 = offs[n + 1];
    float kacc = 0.f;
    float4 m0 = make_float4(0.f, 0.f, 0.f, 0.f);
    float4 m1 = make_float4(0.f, 0.f, 0.f, 0.f);
    int e = o0;
    for (; e + 3 < o1; e += 4) {
        float kk_[4]; uint4 vv[4];
#pragma unroll
        for (int q = 0; q < 4; q++) {
            int s = csr_src[e + q];
            const unsigned char* r = kv0 + (size_t)s * KVROW;
            kk_[q] = bf_lo(((const unsigned short*)r)[lane]);
            vv[q] = *(const uint4*)(r + hoff);
        }
#pragma unroll
        for (int q = 0; q < 4; q++) {
            float ka = kk_[q]; uint4 va = vv[q];
            kacc += ka;
            m0.x = fmaf(ka, bf_lo(va.x), m0.x); m0.y = fmaf(ka, bf_hi(va.x), m0.y);
            m0.z = fmaf(ka, bf_lo(va.y), m0.z); m0.w = fmaf(ka, bf_hi(va.y), m0.w);
            m1.x = fmaf(ka, bf_lo(va.z), m1.x); m1.y = fmaf(ka, bf_hi(va.z), m1.y);
            m1.z = fmaf(ka, bf_lo(va.w), m1.z); m1.w = fmaf(ka, bf_hi(va.w), m1.w);
        }
    }
    for (; e < o1; e++) {
        int s = csr_src[e];
        const unsigned char* r = kv0 + (size_t)s * KVROW;
        float ka = bf_lo(((const unsigned short*)r)[lane]);
        uint4 va = *(const uint4*)(r + hoff);
        kacc += ka;
        m0.x = fmaf(ka, bf_lo(va.x), m0.x); m0.y = fmaf(ka, bf_hi(va.x), m0.y);
        m0.z = fmaf(ka, bf_lo(va.y), m0.z); m0.w = fmaf(ka, bf_hi(va.y), m0.w);
        m1.x = fmaf(ka, bf_lo(va.z), m1.x); m1.y = fmaf(ka, bf_hi(va.z), m1.y);
        m1.z = fmaf(ka, bf_lo(va.w), m1.z); m1.w = fmaf(ka, bf_hi(va.w), m1.w);
    }
    // write S1: K1 bf16 (*dinv), M1 fp8 (*dinv*16; 1/16 folded into hop-1 gamma)
    {
        float dv = dinv[n];
        float s16 = dv * 16.f;
        unsigned char* drow = S1 + (size_t)n * SROW;
        ((unsigned short*)drow)[lane] = f2bf(kacc * dv);
        unsigned u0 = __builtin_amdgcn_cvt_pk_fp8_f32(m0.x * s16, m0.y * s16, 0, false);
        u0 = __builtin_amdgcn_cvt_pk_fp8_f32(m0.z * s16, m0.w * s16, u0, true);
        unsigned u1 = __builtin_amdgcn_cvt_pk_fp8_f32(m1.x * s16, m1.y * s16, 0, false);
        u1 = __builtin_amdgcn_cvt_pk_fp8_f32(m1.z * s16, m1.w * s16, u1, true);
        uint2 pv; pv.x = u0; pv.y = u1;
        *(uint2*)(drow + 128 + lane * 8) = pv;
    }
    // attend
    float qv = Qg[(size_t)n * 64 + lane];
    float hh[8];
    hh[0] = qv * m0.x; hh[1] = qv * m0.y; hh[2] = qv * m0.z; hh[3] = qv * m0.w;
    hh[4] = qv * m1.x; hh[5] = qv * m1.y; hh[6] = qv * m1.z; hh[7] = qv * m1.w;
    float cc = qv * kacc;
#pragma unroll
    for (int s = 1; s < 16; s <<= 1) {
#pragma unroll
        for (int j = 0; j < 8; j++) hh[j] += __shfl_xor(hh[j], s, 16);
        cc += __shfl_xor(cc, s, 16);
    }
    if ((lane & 15) < 8) {
        int j = lane & 7;
        float val = j < 4 ? (j < 2 ? (j == 0 ? hh[0] : hh[1]) : (j == 2 ? hh[2] : hh[3]))
                          : (j < 6 ? (j == 4 ? hh[4] : hh[5]) : (j == 6 ? hh[6] : hh[7]));
        size_t idx = (size_t)n * 32 + h * 8 + j;
        hid[idx] += gam * val / (cc + CSTF);
    }
}

// ---------------- hop 1: gather S1 (bf16 K + fp8 M), attend, unroll-4 --------

__global__ __launch_bounds__(256) void k_prop1(const unsigned char* __restrict__ Sold,
    const int* __restrict__ offs, const int* __restrict__ csr_src,
    const float* __restrict__ Qg, const float* __restrict__ hopwise,
    const float* __restrict__ headwise, float* __restrict__ hid) {
    int t = threadIdx.x;
    int lane = t & 63;
    int n = (blockIdx.x * 256 + t) >> 6;
    if (n >= NN) return;
    int h = lane >> 4;
    float e0 = expf(headwise[1]);
    float e1 = expf(headwise[3]);
    float e2 = expf(headwise[5]);
    float e3 = expf(headwise[7]);
    float esum = e0 + e1 + e2 + e3;
    float eh = (h == 0) ? e0 : ((h == 1) ? e1 : ((h == 2) ? e2 : e3));
    float gam = hopwise[2] * eh / esum * 0.0625f;   // 1/16 M-scale folded in

    int o0 = offs[n], o1 = offs[n + 1];
    float kacc = 0.f;
    float4 m0 = make_float4(0.f, 0.f, 0.f, 0.f);
    float4 m1 = make_float4(0.f, 0.f, 0.f, 0.f);
    int e = o0;
    for (; e + 3 < o1; e += 4) {
        float kk_[4]; uint2 mv[4];
#pragma unroll
        for (int q = 0; q < 4; q++) {
            int s = csr_src[e + q];
            const unsigned char* r = Sold + (size_t)s * SROW;
            kk_[q] = bf_lo(((const unsigned short*)r)[lane]);
            mv[q] = *(const uint2*)(r + 128 + lane * 8);
        }
#pragma unroll
        for (int q = 0; q < 4; q++) {
            kacc += kk_[q];
            f32x2 a0 = __builtin_amdgcn_cvt_pk_f32_fp8(mv[q].x, false);
            f32x2 a1 = __builtin_amdgcn_cvt_pk_f32_fp8(mv[q].x, true);
            f32x2 b0 = __builtin_amdgcn_cvt_pk_f32_fp8(mv[q].y, false);
            f32x2 b1 = __builtin_amdgcn_cvt_pk_f32_fp8(mv[q].y, true);
            m0.x += a0.x; m0.y += a0.y; m0.z += a1.x; m0.w += a1.y;
            m1.x += b0.x; m1.y += b0.y; m1.z += b1.x; m1.w += b1.y;
        }
    }
    for (; e < o1; e++) {
        int s = csr_src[e];
        const unsigned char* r = Sold + (size_t)s * SROW;
        float ka = bf_lo(((const unsigned short*)r)[lane]);
        uint2 mva = *(const uint2*)(r + 128 + lane * 8);
        kacc += ka;
        f32x2 a0 = __builtin_amdgcn_cvt_pk_f32_fp8(mva.x, false);
        f32x2 a1 = __builtin_amdgcn_cvt_pk_f32_fp8(mva.x, true);
        f32x2 b0 = __builtin_amdgcn_cvt_pk_f32_fp8(mva.y, false);
        f32x2 b1 = __builtin_amdgcn_cvt_pk_f32_fp8(mva.y, true);
        m0.x += a0.x; m0.y += a0.y; m0.z += a1.x; m0.w += a1.y;
        m1.x += b0.x; m1.y += b0.y; m1.z += b1.x; m1.w += b1.y;
    }
    float qv = Qg[(size_t)n * 64 + lane];
    float hh[8];
    hh[0] = qv * m0.x; hh[1] = qv * m0.y; hh[2] = qv * m0.z; hh[3] = qv * m0.w;
    hh[4] = qv * m1.x; hh[5] = qv * m1.y; hh[6] = qv * m1.z; hh[7] = qv * m1.w;
    float cc = qv * kacc;
#pragma unroll
    for (int s = 1; s < 16; s <<= 1) {
#pragma unroll
        for (int j = 0; j < 8; j++) hh[j] += __shfl_xor(hh[j], s, 16);
        cc += __shfl_xor(cc, s, 16);
    }
    if ((lane & 15) < 8) {
        int j = lane & 7;
        float val = j < 4 ? (j < 2 ? (j == 0 ? hh[0] : hh[1]) : (j == 2 ? hh[2] : hh[3]))
                          : (j < 6 ? (j == 4 ? hh[4] : hh[5]) : (j == 6 ? hh[6] : hh[7]));
        size_t idx = (size_t)n * 32 + h * 8 + j;
        hid[idx] += gam * val / (cc + CSTF);
    }
}

// ---------------- final: out = hidden @ Wo + bo + teleport * teleportH ----------------

__global__ __launch_bounds__(256) void k_final(const float* __restrict__ hid,
    const float* __restrict__ Qg, const float* __restrict__ Wo,
    const float* __restrict__ bo, const float* __restrict__ tMK,
    const float* __restrict__ teleport, float* __restrict__ out) {
    __shared__ float tm[512];
    __shared__ float tk[64];
    __shared__ float wo[256];
    __shared__ float bos[8];
    int t = threadIdx.x;
    const float invN = 1.0f / (float)NN;
    for (int i = t; i < 512; i += 256) tm[i] = tMK[i] * invN;
    if (t < 64) tk[t] = tMK[512 + t] * invN;
    wo[t] = Wo[t & 255];
    if (t < 8) bos[t] = bo[t];
    __syncthreads();
    float tp = teleport[0];
    int lane = t & 63;
    int sub = lane & 7;
    int g = lane >> 3;
    int wid = (blockIdx.x * 256 + t) >> 6;
    int nwaves = gridDim.x * 4;
    for (int nb = wid * 8; nb < NN; nb += nwaves * 8) {
        int n = nb + g;
        if (n < NN) {
            const float* hrow = hid + (size_t)n * 32;
            const float* qrow = Qg + (size_t)n * 64;
            float o = bos[sub];
#pragma unroll
            for (int m = 0; m < 32; m++) o = fmaf(hrow[m], wo[m * 8 + sub], o);
            float th = 0.f;
#pragma unroll
            for (int h2 = 0; h2 < 4; h2++) {
                float num = 0.f, den = 0.f;
#pragma unroll
                for (int i = 0; i < 16; i++) {
                    float q = qrow[h2 * 16 + i];
                    num = fmaf(q, tm[h2 * 128 + i * 8 + sub], num);
                    den = fmaf(q, tk[h2 * 16 + i], den);
                }
                th += num / (den + CSTF);
            }
            out[(size_t)n * 8 + sub] = o + tp * th;
        }
    }
}

// ---------------- launch ----------------

extern "C" void kernel_launch(void* const* d_in, const int* in_sizes, int n_in,
                              void* d_out, int out_size, void* d_ws, size_t ws_size,
                              hipStream_t stream) {
    const float* nf = (const float*)d_in[0];
    const int* ei = (const int*)d_in[1];
    const float* Wi = (const float*)d_in[2];
    const float* bi = (const float*)d_in[3];
    const float* Wq = (const float*)d_in[4];
    const float* bq = (const float*)d_in[5];
    const float* Wk = (const float*)d_in[6];
    const float* bk = (const float*)d_in[7];
    const float* Wv = (const float*)d_in[8];
    const float* bv = (const float*)d_in[9];
    const float* Wo = (const float*)d_in[10];
    const float* bo = (const float*)d_in[11];
    const float* hopwise = (const float*)d_in[12];
    const float* headwise = (const float*)d_in[13];
    const float* teleport = (const float*)d_in[14];
    float* out = (float*)d_out;

    char* base = (char*)d_ws;
    size_t off = 0;
    auto alloc = [&](size_t bytes) -> void* {
        void* p = base + off;
        off = (off + bytes + 255) & ~(size_t)255;
        return p;
    };
    int* deg = (int*)alloc(NN * 4);
    int* cursor = (int*)alloc(NN * 4);
    int* offs = (int*)alloc((NN + 1) * 4);
    int* bsum = (int*)alloc(256 * 4);
    int* bex = (int*)alloc(256 * 4);
    float* dinv = (float*)alloc(NN * 4);
    int* csr_src = (int*)alloc((size_t)NE * 4);
    unsigned short* Wt = (unsigned short*)alloc(64 * 512 * 2);
    float* xbuf = (float*)alloc((size_t)NN * 64 * 4);
    float* Qg = (float*)alloc((size_t)NN * 64 * 4);
    float* hid = (float*)alloc((size_t)NN * 32 * 4);
    unsigned char* kv0 = (unsigned char*)alloc((size_t)NN * KVROW);
    unsigned char* S1 = (unsigned char*)alloc((size_t)NN * SROW);
    float* tMK = (float*)alloc(576 * 4);

    const int* rowp = ei;
    const int* colp = ei + NE;

    hipMemsetAsync(deg, 0, NN * 4, stream);

    k_deg<<<(NE + 255) / 256, 256, 0, stream>>>(colp, deg);
    k_deginv<<<(NN + 255) / 256, 256, 0, stream>>>(deg, dinv, cursor, tMK);
    k_bsum<<<SCAN_NB, 256, 0, stream>>>(deg, bsum);
    k_bscan<<<1, 256, 0, stream>>>(bsum, bex);
    k_expand<<<SCAN_NB, 256, 0, stream>>>(deg, bex, offs);
    k_scatter<<<(NE + 255) / 256, 256, 0, stream>>>(rowp, colp, offs, cursor, csr_src);
    k_wt<<<128, 256, 0, stream>>>(Wi, Wt);
    k_xgemm<<<NTILES, 256, 0, stream>>>(nf, Wt, bi, xbuf);
    k_qkv<<<512, 256, 0, stream>>>(xbuf, Wq, bq, Wk, bk, Wv, bv, hopwise, dinv,
                                   Qg, hid, kv0, tMK);
    k_hop0<<<(NN * 64 + 255) / 256, 256, 0, stream>>>(kv0, offs, csr_src, dinv, Qg,
                                                      hopwise, headwise, S1, hid);
    k_prop1<<<(NN * 64 + 255) / 256, 256, 0, stream>>>(S1, offs, csr_src, Qg,
                                                       hopwise, headwise, hid);
    k_final<<<1563, 256, 0, stream>>>(hid, Qg, Wo, bo, tMK, teleport, out);
}

// Round 10
// 463.462 us; speedup vs baseline: 1.0686x; 1.0370x over previous
//
#include <hip/hip_runtime.h>
#include <hip/hip_bf16.h>
#include <stdint.h>
#include <stddef.h>

#define NN 50000
#define NE 800000
#define FIN 500
#define HIDN 64
#define NH 4
#define HCD 16
#define NC 8
// kv row: 64 bf16 Kf*dinv (128 B) + 32 bf16 V (64 B) = 192 B
#define KVROW 192
// S1 row: 64 fp8 K1*dinv*8 (64 B) + 512 fp8 M1*dinv*16 (512 B) = 576 B
#define SROW 576
#define CSTF 1e-5f
#define SCAN_NB 196   // ceil(50000/256)
#define NTILES 782    // ceil(50000/64)

typedef float f32x2 __attribute__((ext_vector_type(2)));
typedef __attribute__((ext_vector_type(8))) short bf16x8;
typedef __attribute__((ext_vector_type(4))) float f32x4;

// bf16 helpers (storage-only; math fp32)
__device__ inline float bf_lo(unsigned u) {
    union { unsigned i; float f; } v; v.i = u << 16; return v.f;
}
__device__ inline f32x2 bfpair(unsigned u) {
    union { unsigned i; float f; } lo, hi;
    lo.i = u << 16; hi.i = u & 0xffff0000u;
    f32x2 r; r.x = lo.f; r.y = hi.f; return r;
}
__device__ inline unsigned short f2bf(float f) {
    union { float f; unsigned i; } v; v.f = f;
    unsigned r = v.i + 0x7fffu + ((v.i >> 16) & 1u);   // RNE
    return (unsigned short)(r >> 16);
}
__device__ inline unsigned pack2bf(float a, float b) {
    __hip_bfloat162 h = __float22bfloat162_rn(make_float2(a, b));
    unsigned r; __builtin_memcpy(&r, &h, 4); return r;
}

// ---------------- degree count + Wt transpose (independent, merged) ---------

__global__ void k_deg_wt(const int* __restrict__ col, int* __restrict__ deg,
                         const float* __restrict__ Wi, unsigned short* __restrict__ Wt) {
    int e = blockIdx.x * blockDim.x + threadIdx.x;
    if (e < NE) atomicAdd(&deg[col[e]], 1);
    if (e < 64 * 512) {
        int c = e >> 9;
        int k = e & 511;
        Wt[e] = (k < FIN) ? f2bf(Wi[(size_t)k * 64 + c]) : (unsigned short)0;
    }
}

// ---------------- block sums + deginv + cursor + tMK zero (merged) ----------

__global__ void k_bsum(const int* __restrict__ deg, int* __restrict__ bsum,
                       float* __restrict__ dinv, int* __restrict__ cursor,
                       float* __restrict__ tMK) {
    __shared__ int red[256];
    int b = blockIdx.x, t = threadIdx.x;
    int i = b * 256 + t;
    int d = (i < NN) ? deg[i] : 0;
    if (i < NN) {
        dinv[i] = d > 0 ? 1.0f / (float)d : 0.0f;
        cursor[i] = 0;
    }
    if (b == 0)
        for (int j = t; j < 576; j += 256) tMK[j] = 0.f;
    red[t] = d;
    __syncthreads();
    for (int s = 128; s > 0; s >>= 1) {
        if (t < s) red[t] += red[t + s];
        __syncthreads();
    }
    if (t == 0) bsum[b] = red[0];
}

__global__ void k_bscan(const int* __restrict__ bsum, int* __restrict__ bex) {
    __shared__ int s[256];
    int t = threadIdx.x;
    int own = (t < SCAN_NB) ? bsum[t] : 0;
    s[t] = own;
    __syncthreads();
    for (int d = 1; d < 256; d <<= 1) {
        int v = (t >= d) ? s[t - d] : 0;
        __syncthreads();
        s[t] += v;
        __syncthreads();
    }
    if (t < SCAN_NB) bex[t] = s[t] - own;   // exclusive
}

__global__ void k_expand(const int* __restrict__ deg, const int* __restrict__ bex,
                         int* __restrict__ offs) {
    __shared__ int s[256];
    int b = blockIdx.x, t = threadIdx.x;
    int i = b * 256 + t;
    int v = (i < NN) ? deg[i] : 0;
    s[t] = v;
    __syncthreads();
    for (int d = 1; d < 256; d <<= 1) {
        int a = (t >= d) ? s[t - d] : 0;
        __syncthreads();
        s[t] += a;
        __syncthreads();
    }
    int excl = s[t] - v + bex[b];
    if (i < NN) offs[i] = excl;
    if (i == NN - 1) offs[NN] = excl + v;
}

__global__ void k_scatter(const int* __restrict__ row, const int* __restrict__ col,
                          const int* __restrict__ offs, int* __restrict__ cursor,
                          int* __restrict__ csr_src) {
    int e = blockIdx.x * blockDim.x + threadIdx.x;
    if (e < NE) {
        int c = col[e];
        int pos = offs[c] + atomicAdd(&cursor[c], 1);
        csr_src[pos] = row[e];
    }
}

// ---------------- x = relu(nf @ Wi + bi), bf16 MFMA, NO LDS ----------------
// A-frags direct from global; B-frags from Wt (64 KB, L2-resident).

__global__ __launch_bounds__(256) void k_xgemm(const float* __restrict__ nf,
                                               const unsigned short* __restrict__ Wt,
                                               const float* __restrict__ bi,
                                               float* __restrict__ x) {
    int t = threadIdx.x;
    int lane = t & 63;
    int w = t >> 6;
    int quad = lane >> 4;
    int l15 = lane & 15;
    int n0 = blockIdx.x * 64;
    int rown = n0 + w * 16 + l15;
    const float* arow = &nf[(size_t)(rown < NN ? rown : 0) * FIN];

    f32x4 acc[4];
#pragma unroll
    for (int ct = 0; ct < 4; ct++) acc[ct] = (f32x4){0.f, 0.f, 0.f, 0.f};

    for (int k0 = 0; k0 < 512; k0 += 32) {
        int kk = k0 + quad * 8;
        float4 a0 = make_float4(0.f, 0.f, 0.f, 0.f);
        float4 a1 = make_float4(0.f, 0.f, 0.f, 0.f);
        if (kk < FIN) a0 = *(const float4*)&arow[kk];
        if (kk + 4 < FIN) a1 = *(const float4*)&arow[kk + 4];
        union { unsigned u[4]; bf16x8 v; } A;
        A.u[0] = pack2bf(a0.x, a0.y);
        A.u[1] = pack2bf(a0.z, a0.w);
        A.u[2] = pack2bf(a1.x, a1.y);
        A.u[3] = pack2bf(a1.z, a1.w);
#pragma unroll
        for (int ct = 0; ct < 4; ct++) {
            int c = ct * 16 + l15;
            bf16x8 bfr = *(const bf16x8*)&Wt[(size_t)c * 512 + kk];
            acc[ct] = __builtin_amdgcn_mfma_f32_16x16x32_bf16(A.v, bfr, acc[ct], 0, 0, 0);
        }
    }
#pragma unroll
    for (int ct = 0; ct < 4; ct++) {
        int c = ct * 16 + l15;
        float bv = bi[c];
#pragma unroll
        for (int r = 0; r < 4; r++) {
            int n = n0 + w * 16 + quad * 4 + r;
            if (n < NN)
                x[(size_t)n * 64 + c] = fmaxf(acc[ct][r] + bv, 0.f);
        }
    }
}

// ---------------- QKV + kv row + teleport sums ----------------

__global__ __launch_bounds__(256) void k_qkv(const float* __restrict__ x,
    const float* __restrict__ Wq, const float* __restrict__ bq,
    const float* __restrict__ Wk, const float* __restrict__ bk,
    const float* __restrict__ Wv, const float* __restrict__ bv,
    const float* __restrict__ hopwise, const float* __restrict__ dinv,
    float* __restrict__ Qg, float* __restrict__ hid,
    unsigned char* __restrict__ kv0, float* __restrict__ tMK) {
    __shared__ float wq_s[64 * 64], wk_s[64 * 64], wv_s[64 * 32];
    __shared__ float bq_s[64], bk_s[64], bv_s[32];
    __shared__ float xs[4][8][64];
    __shared__ float tacc[576];
    int t = threadIdx.x;
    for (int i = t; i < 4096; i += 256) { wq_s[i] = Wq[i]; wk_s[i] = Wk[i]; }
    for (int i = t; i < 2048; i += 256) wv_s[i] = Wv[i];
    if (t < 64) { bq_s[t] = bq[t]; bk_s[t] = bk[t]; }
    if (t >= 64 && t < 96) bv_s[t - 64] = bv[t - 64];
    for (int i = t; i < 576; i += 256) tacc[i] = 0.f;
    __syncthreads();
    int lane = t & 63;
    int w = t >> 6;
    int h = lane >> 4;
    int vcol = lane & 31;
    float hw0 = hopwise[0];
    float tkp = 0.f;
    float tmp_[8];
#pragma unroll
    for (int j = 0; j < 8; j++) tmp_[j] = 0.f;
    int tiles = (NN + 31) >> 5;
    for (int tile = blockIdx.x; tile < tiles; tile += gridDim.x) {
        int n0 = tile * 32 + w * 8;
        __syncthreads();
#pragma unroll
        for (int u = 0; u < 8; u++) {
            int n = n0 + u;
            xs[w][u][lane] = (n < NN) ? x[(size_t)n * 64 + lane] : 0.f;
        }
        __syncthreads();
        float aq[8], ak[8], av[8];
#pragma unroll
        for (int u = 0; u < 8; u++) { aq[u] = 0.f; ak[u] = 0.f; av[u] = 0.f; }
        for (int f = 0; f < 64; f++) {
            float wqv = wq_s[f * 64 + lane];
            float wkv = wk_s[f * 64 + lane];
            float wvv = wv_s[f * 32 + vcol];
#pragma unroll
            for (int u = 0; u < 8; u++) {
                float xf = xs[w][u][f];
                aq[u] = fmaf(xf, wqv, aq[u]);
                ak[u] = fmaf(xf, wkv, ak[u]);
                av[u] = fmaf(xf, wvv, av[u]);
            }
        }
#pragma unroll
        for (int u = 0; u < 8; u++) {
            int n = n0 + u;
            float q = aq[u] + bq_s[lane];
            float k = ak[u] + bk_s[lane];
            float v = av[u] + bv_s[vcol];
            float Qv = q > 0.f ? 1.f + q : expf(q);   // 1 + elu
            float Kv = k > 0.f ? 1.f + k : expf(k);
            if (n < NN) {
                Qg[(size_t)n * 64 + lane] = Qv;
                float vj[8];
#pragma unroll
                for (int j = 0; j < 8; j++) vj[j] = __shfl(v, h * 8 + j, 64);
                tkp += Kv;
#pragma unroll
                for (int j = 0; j < 8; j++) tmp_[j] += Kv * vj[j];
                float dv = dinv[n];
                unsigned short* kvrow = (unsigned short*)(kv0 + (size_t)n * KVROW);
                kvrow[lane] = f2bf(Kv * dv);
                if (lane < 32) kvrow[64 + lane] = f2bf(v);
                if (lane < 32) hid[(size_t)n * 32 + lane] = v * hw0;
            }
        }
    }
#pragma unroll
    for (int j = 0; j < 8; j++) atomicAdd(&tacc[lane * 8 + j], tmp_[j]);
    atomicAdd(&tacc[512 + lane], tkp);
    __syncthreads();
    for (int i = t; i < 576; i += 256) atomicAdd(&tMK[i], tacc[i]);
}

// ---------------- hop 0: gather Kf/V, outer-product on the fly --------------
// One wave per node; unroll-8; f32x2 packed accumulate.

__global__ __launch_bounds__(256) void k_hop0(const unsigned char* __restrict__ kv0,
    const int* __restrict__ offs, const int* __restrict__ csr_src,
    const float* __restrict__ dinv, const float* __restrict__ Qg,
    const float* __restrict__ hopwise, const float* __restrict__ headwise,
    unsigned char* __restrict__ S1, float* __restrict__ hid) {
    int t = threadIdx.x;
    int lane = t & 63;
    int n = __builtin_amdgcn_readfirstlane((blockIdx.x * 256 + t) >> 6);
    if (n >= NN) return;
    int h = lane >> 4;
    float e0 = expf(headwise[0]);
    float e1 = expf(headwise[2]);
    float e2 = expf(headwise[4]);
    float e3 = expf(headwise[6]);
    float esum = e0 + e1 + e2 + e3;
    float eh = (h == 0) ? e0 : ((h == 1) ? e1 : ((h == 2) ? e2 : e3));
    float gam = hopwise[1] * eh / esum;

    int hoff = 128 + h * 16;
    int o0 = offs[n], o1 = offs[n + 1];
    float kacc = 0.f;
    f32x2 A0 = {0.f, 0.f}, A1 = {0.f, 0.f}, B0 = {0.f, 0.f}, B1 = {0.f, 0.f};
    int e = o0;
    for (; e + 7 < o1; e += 8) {
        float kk_[8]; uint4 vv[8];
#pragma unroll
        for (int q = 0; q < 8; q++) {
            int s = csr_src[e + q];
            const unsigned char* r = kv0 + (size_t)s * KVROW;
            kk_[q] = bf_lo(((const unsigned short*)r)[lane]);
            vv[q] = *(const uint4*)(r + hoff);
        }
#pragma unroll
        for (int q = 0; q < 8; q++) {
            float ka = kk_[q];
            f32x2 ka2; ka2.x = ka; ka2.y = ka;
            kacc += ka;
            A0 += ka2 * bfpair(vv[q].x);
            A1 += ka2 * bfpair(vv[q].y);
            B0 += ka2 * bfpair(vv[q].z);
            B1 += ka2 * bfpair(vv[q].w);
        }
    }
    for (; e < o1; e++) {
        int s = csr_src[e];
        const unsigned char* r = kv0 + (size_t)s * KVROW;
        float ka = bf_lo(((const unsigned short*)r)[lane]);
        uint4 va = *(const uint4*)(r + hoff);
        f32x2 ka2; ka2.x = ka; ka2.y = ka;
        kacc += ka;
        A0 += ka2 * bfpair(va.x);
        A1 += ka2 * bfpair(va.y);
        B0 += ka2 * bfpair(va.z);
        B1 += ka2 * bfpair(va.w);
    }
    // write S1: K fp8 (*dinv*8), M fp8 (*dinv*16); scales folded into hop-1
    {
        float dv = dinv[n];
        float s8 = dv * 8.f;
        float s16 = dv * 16.f;
        unsigned char* drow = S1 + (size_t)n * SROW;
        unsigned kb8 = __builtin_amdgcn_cvt_pk_fp8_f32(kacc * s8, 0.f, 0, false);
        drow[lane] = (unsigned char)(kb8 & 0xff);
        unsigned u0 = __builtin_amdgcn_cvt_pk_fp8_f32(A0.x * s16, A0.y * s16, 0, false);
        u0 = __builtin_amdgcn_cvt_pk_fp8_f32(A1.x * s16, A1.y * s16, u0, true);
        unsigned u1 = __builtin_amdgcn_cvt_pk_fp8_f32(B0.x * s16, B0.y * s16, 0, false);
        u1 = __builtin_amdgcn_cvt_pk_fp8_f32(B1.x * s16, B1.y * s16, u1, true);
        uint2 pv; pv.x = u0; pv.y = u1;
        *(uint2*)(drow + 64 + lane * 8) = pv;
    }
    // attend (true-scale)
    float qv = Qg[(size_t)n * 64 + lane];
    float hh[8];
    hh[0] = qv * A0.x; hh[1] = qv * A0.y; hh[2] = qv * A1.x; hh[3] = qv * A1.y;
    hh[4] = qv * B0.x; hh[5] = qv * B0.y; hh[6] = qv * B1.x; hh[7] = qv * B1.y;
    float cc = qv * kacc;
#pragma unroll
    for (int s = 1; s < 16; s <<= 1) {
#pragma unroll
        for (int j = 0; j < 8; j++) hh[j] += __shfl_xor(hh[j], s, 16);
        cc += __shfl_xor(cc, s, 16);
    }
    if ((lane & 15) < 8) {
        int j = lane & 7;
        float val = j < 4 ? (j < 2 ? (j == 0 ? hh[0] : hh[1]) : (j == 2 ? hh[2] : hh[3]))
                          : (j < 6 ? (j == 4 ? hh[4] : hh[5]) : (j == 6 ? hh[6] : hh[7]));
        size_t idx = (size_t)n * 32 + h * 8 + j;
        hid[idx] += gam * val / (cc + CSTF);
    }
}

// ---------------- hop 1: gather S1 (fp8 K + fp8 M), attend, unroll-8 --------

__global__ __launch_bounds__(256) void k_prop1(const unsigned char* __restrict__ Sold,
    const int* __restrict__ offs, const int* __restrict__ csr_src,
    const float* __restrict__ Qg, const float* __restrict__ hopwise,
    const float* __restrict__ headwise, float* __restrict__ hid) {
    int t = threadIdx.x;
    int lane = t & 63;
    int n = __builtin_amdgcn_readfirstlane((blockIdx.x * 256 + t) >> 6);
    if (n >= NN) return;
    int h = lane >> 4;
    float e0 = expf(headwise[1]);
    float e1 = expf(headwise[3]);
    float e2 = expf(headwise[5]);
    float e3 = expf(headwise[7]);
    float esum = e0 + e1 + e2 + e3;
    float eh = (h == 0) ? e0 : ((h == 1) ? e1 : ((h == 2) ? e2 : e3));
    float gam = hopwise[2] * eh / esum * 0.0625f;   // 1/16 M-scale folded in

    int o0 = offs[n], o1 = offs[n + 1];
    float kacc = 0.f;
    f32x2 A0 = {0.f, 0.f}, A1 = {0.f, 0.f}, B0 = {0.f, 0.f}, B1 = {0.f, 0.f};
    int e = o0;
    for (; e + 7 < o1; e += 8) {
        unsigned kb[8]; uint2 mv[8];
#pragma unroll
        for (int q = 0; q < 8; q++) {
            int s = csr_src[e + q];
            const unsigned char* r = Sold + (size_t)s * SROW;
            kb[q] = r[lane];
            mv[q] = *(const uint2*)(r + 64 + lane * 8);
        }
#pragma unroll
        for (int q = 0; q < 8; q++) {
            f32x2 kv = __builtin_amdgcn_cvt_pk_f32_fp8(kb[q], false);
            kacc += kv.x;
            A0 += __builtin_amdgcn_cvt_pk_f32_fp8(mv[q].x, false);
            A1 += __builtin_amdgcn_cvt_pk_f32_fp8(mv[q].x, true);
            B0 += __builtin_amdgcn_cvt_pk_f32_fp8(mv[q].y, false);
            B1 += __builtin_amdgcn_cvt_pk_f32_fp8(mv[q].y, true);
        }
    }
    for (; e < o1; e++) {
        int s = csr_src[e];
        const unsigned char* r = Sold + (size_t)s * SROW;
        unsigned kb = r[lane];
        uint2 mva = *(const uint2*)(r + 64 + lane * 8);
        f32x2 kv = __builtin_amdgcn_cvt_pk_f32_fp8(kb, false);
        kacc += kv.x;
        A0 += __builtin_amdgcn_cvt_pk_f32_fp8(mva.x, false);
        A1 += __builtin_amdgcn_cvt_pk_f32_fp8(mva.x, true);
        B0 += __builtin_amdgcn_cvt_pk_f32_fp8(mva.y, false);
        B1 += __builtin_amdgcn_cvt_pk_f32_fp8(mva.y, true);
    }
    kacc *= 0.125f;   // undo K fp8 storage scale (x8)
    float qv = Qg[(size_t)n * 64 + lane];
    float hh[8];
    hh[0] = qv * A0.x; hh[1] = qv * A0.y; hh[2] = qv * A1.x; hh[3] = qv * A1.y;
    hh[4] = qv * B0.x; hh[5] = qv * B0.y; hh[6] = qv * B1.x; hh[7] = qv * B1.y;
    float cc = qv * kacc;
#pragma unroll
    for (int s = 1; s < 16; s <<= 1) {
#pragma unroll
        for (int j = 0; j < 8; j++) hh[j] += __shfl_xor(hh[j], s, 16);
        cc += __shfl_xor(cc, s, 16);
    }
    if ((lane & 15) < 8) {
        int j = lane & 7;
        float val = j < 4 ? (j < 2 ? (j == 0 ? hh[0] : hh[1]) : (j == 2 ? hh[2] : hh[3]))
                          : (j < 6 ? (j == 4 ? hh[4] : hh[5]) : (j == 6 ? hh[6] : hh[7]));
        size_t idx = (size_t)n * 32 + h * 8 + j;
        hid[idx] += gam * val / (cc + CSTF);
    }
}

// ---------------- final: out = hidden @ Wo + bo + teleport * teleportH ------

__global__ __launch_bounds__(256) void k_final(const float* __restrict__ hid,
    const float* __restrict__ Qg, const float* __restrict__ Wo,
    const float* __restrict__ bo, const float* __restrict__ tMK,
    const float* __restrict__ teleport, float* __restrict__ out) {
    __shared__ float tm[512];
    __shared__ float tk[64];
    __shared__ float wo[256];
    __shared__ float bos[8];
    int t = threadIdx.x;
    const float invN = 1.0f / (float)NN;
    for (int i = t; i < 512; i += 256) tm[i] = tMK[i] * invN;
    if (t < 64) tk[t] = tMK[512 + t] * invN;
    wo[t] = Wo[t & 255];
    if (t < 8) bos[t] = bo[t];
    __syncthreads();
    float tp = teleport[0];
    int lane = t & 63;
    int sub = lane & 7;
    int g = lane >> 3;
    int wid = (blockIdx.x * 256 + t) >> 6;
    int nwaves = gridDim.x * 4;
    for (int nb = wid * 8; nb < NN; nb += nwaves * 8) {
        int n = nb + g;
        if (n < NN) {
            const float* hrow = hid + (size_t)n * 32;
            const float* qrow = Qg + (size_t)n * 64;
            float o = bos[sub];
#pragma unroll
            for (int m = 0; m < 32; m++) o = fmaf(hrow[m], wo[m * 8 + sub], o);
            float th = 0.f;
#pragma unroll
            for (int h2 = 0; h2 < 4; h2++) {
                float num = 0.f, den = 0.f;
#pragma unroll
                for (int i = 0; i < 16; i++) {
                    float q = qrow[h2 * 16 + i];
                    num = fmaf(q, tm[h2 * 128 + i * 8 + sub], num);
                    den = fmaf(q, tk[h2 * 16 + i], den);
                }
                th += num / (den + CSTF);
            }
            out[(size_t)n * 8 + sub] = o + tp * th;
        }
    }
}

// ---------------- launch ----------------

extern "C" void kernel_launch(void* const* d_in, const int* in_sizes, int n_in,
                              void* d_out, int out_size, void* d_ws, size_t ws_size,
                              hipStream_t stream) {
    const float* nf = (const float*)d_in[0];
    const int* ei = (const int*)d_in[1];
    const float* Wi = (const float*)d_in[2];
    const float* bi = (const float*)d_in[3];
    const float* Wq = (const float*)d_in[4];
    const float* bq = (const float*)d_in[5];
    const float* Wk = (const float*)d_in[6];
    const float* bk = (const float*)d_in[7];
    const float* Wv = (const float*)d_in[8];
    const float* bv = (const float*)d_in[9];
    const float* Wo = (const float*)d_in[10];
    const float* bo = (const float*)d_in[11];
    const float* hopwise = (const float*)d_in[12];
    const float* headwise = (const float*)d_in[13];
    const float* teleport = (const float*)d_in[14];
    float* out = (float*)d_out;

    char* base = (char*)d_ws;
    size_t off = 0;
    auto alloc = [&](size_t bytes) -> void* {
        void* p = base + off;
        off = (off + bytes + 255) & ~(size_t)255;
        return p;
    };
    int* deg = (int*)alloc(NN * 4);
    int* cursor = (int*)alloc(NN * 4);
    int* offs = (int*)alloc((NN + 1) * 4);
    int* bsum = (int*)alloc(256 * 4);
    int* bex = (int*)alloc(256 * 4);
    float* dinv = (float*)alloc(NN * 4);
    int* csr_src = (int*)alloc((size_t)NE * 4);
    unsigned short* Wt = (unsigned short*)alloc(64 * 512 * 2);
    float* xbuf = (float*)alloc((size_t)NN * 64 * 4);
    float* Qg = (float*)alloc((size_t)NN * 64 * 4);
    float* hid = (float*)alloc((size_t)NN * 32 * 4);
    unsigned char* kv0 = (unsigned char*)alloc((size_t)NN * KVROW);
    unsigned char* S1 = (unsigned char*)alloc((size_t)NN * SROW);
    float* tMK = (float*)alloc(576 * 4);

    const int* rowp = ei;
    const int* colp = ei + NE;

    hipMemsetAsync(deg, 0, NN * 4, stream);

    k_deg_wt<<<(NE + 255) / 256, 256, 0, stream>>>(colp, deg, Wi, Wt);
    k_bsum<<<SCAN_NB, 256, 0, stream>>>(deg, bsum, dinv, cursor, tMK);
    k_bscan<<<1, 256, 0, stream>>>(bsum, bex);
    k_expand<<<SCAN_NB, 256, 0, stream>>>(deg, bex, offs);
    k_scatter<<<(NE + 255) / 256, 256, 0, stream>>>(rowp, colp, offs, cursor, csr_src);
    k_xgemm<<<NTILES, 256, 0, stream>>>(nf, Wt, bi, xbuf);
    k_qkv<<<768, 256, 0, stream>>>(xbuf, Wq, bq, Wk, bk, Wv, bv, hopwise, dinv,
                                   Qg, hid, kv0, tMK);
    k_hop0<<<(NN * 64 + 255) / 256, 256, 0, stream>>>(kv0, offs, csr_src, dinv, Qg,
                                                      hopwise, headwise, S1, hid);
    k_prop1<<<(NN * 64 + 255) / 256, 256, 0, stream>>>(S1, offs, csr_src, Qg,
                                                       hopwise, headwise, hid);
    k_final<<<1563, 256, 0, stream>>>(hid, Qg, Wo, bo, tMK, teleport, out);
}